// Round 1
// baseline (3083.243 us; speedup 1.0000x reference)
//
#include <hip/hip_runtime.h>

#define DIM 128
#define TN 32

// ---------------- zero out + counts ----------------
__global__ __launch_bounds__(256)
void zero2_kernel(float* __restrict__ a, int na, float* __restrict__ b, int nb) {
    int i = blockIdx.x * 256 + threadIdx.x;
    if (i < na) a[i] = 0.0f;
    if (i < nb) b[i] = 0.0f;
}

// ---------------- copy (float4) ----------------
__global__ __launch_bounds__(256)
void copy4_kernel(float4* __restrict__ dst, const float4* __restrict__ src, int n4) {
    int i = blockIdx.x * 256 + threadIdx.x;
    if (i < n4) dst[i] = src[i];
}

// ---------------- edge scatter: agg[dst] += X[src] ----------------
// 32 threads per edge, each thread handles 4 consecutive floats.
__global__ __launch_bounds__(256)
void scatter_kernel(const float* __restrict__ X, const int* __restrict__ srcIdx,
                    const int* __restrict__ dstIdx, float* __restrict__ agg, int ne) {
    int i = blockIdx.x * 256 + threadIdx.x;
    int e = i >> 5;
    if (e >= ne) return;
    int c = (i & 31) << 2;
    int s = srcIdx[e];
    int d = dstIdx[e];
    float4 v = *(const float4*)(X + (size_t)s * DIM + c);
    float* p = agg + (size_t)d * DIM + c;
    atomicAdd(p + 0, v.x);
    atomicAdd(p + 1, v.y);
    atomicAdd(p + 2, v.z);
    atomicAdd(p + 3, v.w);
}

// ---------------- fused MLP: Y = relu(X@Wa + ba) @ Wb + bb ----------------
// Block: 256 threads, TN=32 nodes. Wa/Wb staged in 64KB LDS sequentially.
// Thread (fg = tid&15, ng = tid>>4) computes 2 nodes x 8 feats.
__global__ __launch_bounds__(256)
void mlp2_kernel(const float* __restrict__ X, float* __restrict__ Y,
                 const float* __restrict__ Wa, const float* __restrict__ ba,
                 const float* __restrict__ Wb, const float* __restrict__ bb,
                 int n) {
    __shared__ float Ws[DIM * DIM];        // 64 KB
    __shared__ float Xs[TN][DIM + 4];      // pad +4 floats to break bank conflicts
    const int tid = threadIdx.x;
    const int node0 = blockIdx.x * TN;

    // stage X tile (zero-pad OOB rows)
    for (int i = tid; i < TN * (DIM / 4); i += 256) {
        const int nn = i >> 5;
        const int c4 = (i & 31) << 2;
        const int gn = node0 + nn;
        float4 v = make_float4(0.f, 0.f, 0.f, 0.f);
        if (gn < n) v = *(const float4*)(X + (size_t)gn * DIM + c4);
        *(float4*)(&Xs[nn][c4]) = v;
    }
    // stage Wa
    for (int i = tid; i < DIM * DIM / 4; i += 256)
        *(float4*)(&Ws[4 * i]) = *(const float4*)(Wa + 4 * i);
    __syncthreads();

    const int fg = tid & 15, ng = tid >> 4;
    const int f0 = fg * 8, n0 = ng * 2;

    float acc[2][8];
    {
        const float4 bA = *(const float4*)(ba + f0);
        const float4 bB = *(const float4*)(ba + f0 + 4);
        acc[0][0] = bA.x; acc[0][1] = bA.y; acc[0][2] = bA.z; acc[0][3] = bA.w;
        acc[0][4] = bB.x; acc[0][5] = bB.y; acc[0][6] = bB.z; acc[0][7] = bB.w;
        #pragma unroll
        for (int i = 0; i < 8; ++i) acc[1][i] = acc[0][i];
    }
    // GEMM 1: T = X @ Wa + ba
    #pragma unroll 4
    for (int k = 0; k < DIM; ++k) {
        const float x0 = Xs[n0][k];
        const float x1 = Xs[n0 + 1][k];
        const float* wr = &Ws[k * DIM + f0];
        #pragma unroll
        for (int h = 0; h < 2; ++h) {
            const float4 w = *(const float4*)(wr + 4 * h);
            acc[0][4*h+0] = fmaf(x0, w.x, acc[0][4*h+0]);
            acc[0][4*h+1] = fmaf(x0, w.y, acc[0][4*h+1]);
            acc[0][4*h+2] = fmaf(x0, w.z, acc[0][4*h+2]);
            acc[0][4*h+3] = fmaf(x0, w.w, acc[0][4*h+3]);
            acc[1][4*h+0] = fmaf(x1, w.x, acc[1][4*h+0]);
            acc[1][4*h+1] = fmaf(x1, w.y, acc[1][4*h+1]);
            acc[1][4*h+2] = fmaf(x1, w.z, acc[1][4*h+2]);
            acc[1][4*h+3] = fmaf(x1, w.w, acc[1][4*h+3]);
        }
    }
    // ReLU
    #pragma unroll
    for (int j = 0; j < 2; ++j)
        #pragma unroll
        for (int i = 0; i < 8; ++i) acc[j][i] = fmaxf(acc[j][i], 0.0f);

    __syncthreads();  // everyone done reading Xs/Ws

    // write T back to Xs; reload Ws with Wb
    #pragma unroll
    for (int j = 0; j < 2; ++j) {
        *(float4*)(&Xs[n0 + j][f0])     = make_float4(acc[j][0], acc[j][1], acc[j][2], acc[j][3]);
        *(float4*)(&Xs[n0 + j][f0 + 4]) = make_float4(acc[j][4], acc[j][5], acc[j][6], acc[j][7]);
    }
    for (int i = tid; i < DIM * DIM / 4; i += 256)
        *(float4*)(&Ws[4 * i]) = *(const float4*)(Wb + 4 * i);
    __syncthreads();

    // GEMM 2: Y = T @ Wb + bb
    {
        const float4 bA = *(const float4*)(bb + f0);
        const float4 bB = *(const float4*)(bb + f0 + 4);
        acc[0][0] = bA.x; acc[0][1] = bA.y; acc[0][2] = bA.z; acc[0][3] = bA.w;
        acc[0][4] = bB.x; acc[0][5] = bB.y; acc[0][6] = bB.z; acc[0][7] = bB.w;
        #pragma unroll
        for (int i = 0; i < 8; ++i) acc[1][i] = acc[0][i];
    }
    #pragma unroll 4
    for (int k = 0; k < DIM; ++k) {
        const float x0 = Xs[n0][k];
        const float x1 = Xs[n0 + 1][k];
        const float* wr = &Ws[k * DIM + f0];
        #pragma unroll
        for (int h = 0; h < 2; ++h) {
            const float4 w = *(const float4*)(wr + 4 * h);
            acc[0][4*h+0] = fmaf(x0, w.x, acc[0][4*h+0]);
            acc[0][4*h+1] = fmaf(x0, w.y, acc[0][4*h+1]);
            acc[0][4*h+2] = fmaf(x0, w.z, acc[0][4*h+2]);
            acc[0][4*h+3] = fmaf(x0, w.w, acc[0][4*h+3]);
            acc[1][4*h+0] = fmaf(x1, w.x, acc[1][4*h+0]);
            acc[1][4*h+1] = fmaf(x1, w.y, acc[1][4*h+1]);
            acc[1][4*h+2] = fmaf(x1, w.z, acc[1][4*h+2]);
            acc[1][4*h+3] = fmaf(x1, w.w, acc[1][4*h+3]);
        }
    }
    // store
    #pragma unroll
    for (int j = 0; j < 2; ++j) {
        const int gn = node0 + n0 + j;
        if (gn < n) {
            *(float4*)(Y + (size_t)gn * DIM + f0)     = make_float4(acc[j][0], acc[j][1], acc[j][2], acc[j][3]);
            *(float4*)(Y + (size_t)gn * DIM + f0 + 4) = make_float4(acc[j][4], acc[j][5], acc[j][6], acc[j][7]);
        }
    }
}

// ---------------- pool: sums[batch[n]] += H[n]; counts[batch[n]] += 1 ----------------
__global__ __launch_bounds__(256)
void pool_kernel(const float* __restrict__ H, const int* __restrict__ batch,
                 float* __restrict__ sums, float* __restrict__ counts, int n) {
    int i = blockIdx.x * 256 + threadIdx.x;
    int node = i >> 5;
    if (node >= n) return;
    int c = (i & 31) << 2;
    int g = batch[node];
    float4 v = *(const float4*)(H + (size_t)node * DIM + c);
    float* p = sums + (size_t)g * DIM + c;
    atomicAdd(p + 0, v.x);
    atomicAdd(p + 1, v.y);
    atomicAdd(p + 2, v.z);
    atomicAdd(p + 3, v.w);
    if ((i & 31) == 0) atomicAdd(counts + g, 1.0f);
}

__global__ __launch_bounds__(256)
void div_kernel(float* __restrict__ out, const float* __restrict__ counts, int n) {
    int i = blockIdx.x * 256 + threadIdx.x;
    if (i < n) out[i] /= fmaxf(counts[i >> 7], 1.0f);
}

extern "C" void kernel_launch(void* const* d_in, const int* in_sizes, int n_in,
                              void* d_out, int out_size, void* d_ws, size_t ws_size,
                              hipStream_t stream) {
    const float* x    = (const float*)d_in[0];
    const int*   ei   = (const int*)d_in[1];
    const int*   batch = (const int*)d_in[2];
    const float* W1a = (const float*)d_in[3];
    const float* b1a = (const float*)d_in[4];
    const float* W1b = (const float*)d_in[5];
    const float* b1b = (const float*)d_in[6];
    const float* W2a = (const float*)d_in[7];
    const float* b2a = (const float*)d_in[8];
    const float* W2b = (const float*)d_in[9];
    const float* b2b = (const float*)d_in[10];
    float* out = (float*)d_out;

    const int NN = in_sizes[0] / DIM;    // 50000
    const int NE = in_sizes[1] / 2;      // 800000
    const int NG = out_size / DIM;       // 512

    float* bufA   = (float*)d_ws;
    float* bufB   = bufA + (size_t)NN * DIM;
    float* counts = bufB + (size_t)NN * DIM;

    const int* srcIdx = ei;
    const int* dstIdx = ei + NE;

    const int n4 = NN * (DIM / 4);
    const int copyBlocks    = (n4 + 255) / 256;
    const int scatterBlocks = (NE * 32 + 255) / 256;
    const int mlpBlocks     = (NN + TN - 1) / TN;
    const int poolBlocks    = (NN * 32 + 255) / 256;
    const int zeroBlocks    = (out_size + 255) / 256;
    const int divBlocks     = (out_size + 255) / 256;

    // zero the pooled output + counts
    zero2_kernel<<<zeroBlocks, 256, 0, stream>>>(out, out_size, counts, NG);

    // ---- layer 1 ----
    copy4_kernel<<<copyBlocks, 256, 0, stream>>>((float4*)bufA, (const float4*)x, n4);
    scatter_kernel<<<scatterBlocks, 256, 0, stream>>>(x, srcIdx, dstIdx, bufA, NE);
    mlp2_kernel<<<mlpBlocks, 256, 0, stream>>>(bufA, bufB, W1a, b1a, W1b, b1b, NN);

    // ---- layer 2 ----
    copy4_kernel<<<copyBlocks, 256, 0, stream>>>((float4*)bufA, (const float4*)bufB, n4);
    scatter_kernel<<<scatterBlocks, 256, 0, stream>>>(bufB, srcIdx, dstIdx, bufA, NE);
    mlp2_kernel<<<mlpBlocks, 256, 0, stream>>>(bufA, bufB, W2a, b2a, W2b, b2b, NN);

    // ---- pool ----
    pool_kernel<<<poolBlocks, 256, 0, stream>>>(bufB, batch, out, counts, NN);
    div_kernel<<<divBlocks, 256, 0, stream>>>(out, counts, out_size);
}

// Round 2
// 453.545 us; speedup vs baseline: 6.7981x; 6.7981x over previous
//
#include <hip/hip_runtime.h>

#define DIM 128
#define TN 64            // nodes per MLP block
#define MLP_THREADS 512
#define WT_STRIDE 1028   // floats per feature-group in swizzled W layout (===4 mod 32, 16B aligned)

// ---------------- zero two int arrays ----------------
__global__ __launch_bounds__(256)
void zero_int2_kernel(int* __restrict__ a, int na, int* __restrict__ b, int nb) {
    int i = blockIdx.x * 256 + threadIdx.x;
    if (i < na) a[i] = 0;
    if (i < nb) b[i] = 0;
}

// ---------------- histogram: cnt[idx[i]]++ ----------------
__global__ __launch_bounds__(256)
void hist_kernel(const int* __restrict__ idx, int* __restrict__ cnt, int n) {
    int i = blockIdx.x * 256 + threadIdx.x;
    if (i < n) atomicAdd(&cnt[idx[i]], 1);
}

// ---------------- single-block exclusive scan (in place) ----------------
__device__ inline int wave_iscan(int v) {
    int lane = threadIdx.x & 63;
    #pragma unroll
    for (int d = 1; d < 64; d <<= 1) {
        int t = __shfl_up(v, d, 64);
        if (lane >= d) v += t;
    }
    return v;
}

__global__ __launch_bounds__(1024)
void scan_excl_kernel(int* __restrict__ a, int n) {
    __shared__ int wsum[16];
    __shared__ int s_carry;
    const int tid = threadIdx.x;
    const int lane = tid & 63, wv = tid >> 6;
    if (tid == 0) s_carry = 0;
    __syncthreads();
    for (int base = 0; base < n; base += 1024) {
        const int i = base + tid;
        const int v = (i < n) ? a[i] : 0;
        const int isc = wave_iscan(v);          // inclusive within wave
        if (lane == 63) wsum[wv] = isc;
        __syncthreads();
        const int carry = s_carry;
        if (wv == 0) {
            int ws = (lane < 16) ? wsum[lane] : 0;
            int wisc = wave_iscan(ws);
            if (lane < 16) wsum[lane] = wisc - ws;  // exclusive wave offsets
        }
        __syncthreads();
        const int excl = carry + wsum[wv] + isc - v;
        if (i < n) a[i] = excl;
        __syncthreads();
        if (tid == 1023) s_carry = excl + v;    // carry + chunk total
        __syncthreads();
    }
}

// ---------------- CSR fill: csr[pos++] = src, cursor in off ----------------
// After this, off[i] holds END of node i's range (start = off[i-1] or 0).
__global__ __launch_bounds__(256)
void fill_kernel(const int* __restrict__ srcIdx, const int* __restrict__ dstIdx,
                 int* __restrict__ off, int* __restrict__ csr, int ne) {
    int e = blockIdx.x * 256 + threadIdx.x;
    if (e < ne) {
        int p = atomicAdd(&off[dstIdx[e]], 1);
        csr[p] = srcIdx[e];
    }
}

// ---------------- gather aggregate: H[n] = X[n] + sum_{e in CSR(n)} X[csr[e]] ----------------
// One wave per node; lane owns 2 consecutive columns (float2, 512B per row read).
__global__ __launch_bounds__(256)
void gather_kernel(const float* __restrict__ X, const int* __restrict__ csr,
                   const int* __restrict__ off, float* __restrict__ H, int n) {
    const int wid = (blockIdx.x * 256 + threadIdx.x) >> 6;
    const int lane = threadIdx.x & 63;
    if (wid >= n) return;
    const int start = (wid > 0) ? off[wid - 1] : 0;
    const int end = off[wid];
    const int c = lane * 2;
    float2 acc = *(const float2*)(X + (size_t)wid * DIM + c);   // self term
    int e = start;
    for (; e + 4 <= end; e += 4) {
        const int s0 = csr[e], s1 = csr[e + 1], s2 = csr[e + 2], s3 = csr[e + 3];
        const float2 v0 = *(const float2*)(X + (size_t)s0 * DIM + c);
        const float2 v1 = *(const float2*)(X + (size_t)s1 * DIM + c);
        const float2 v2 = *(const float2*)(X + (size_t)s2 * DIM + c);
        const float2 v3 = *(const float2*)(X + (size_t)s3 * DIM + c);
        acc.x += (v0.x + v1.x) + (v2.x + v3.x);
        acc.y += (v0.y + v1.y) + (v2.y + v3.y);
    }
    for (; e < end; ++e) {
        const int s = csr[e];
        const float2 v = *(const float2*)(X + (size_t)s * DIM + c);
        acc.x += v.x; acc.y += v.y;
    }
    *(float2*)(H + (size_t)wid * DIM + c) = acc;
}

// ---------------- fused MLP: Y = relu(X@Wa + ba) @ Wb + bb ----------------
// 512 threads, TN=64 nodes/block. W staged into bank-conflict-free layout:
// Wt[fb*WT_STRIDE + k*8 + j] = W[k*128 + fb*8 + j]; WT_STRIDE%32==4 -> 2-way (free).
__global__ __launch_bounds__(MLP_THREADS)
void mlp2_kernel(const float* __restrict__ X, float* __restrict__ Y,
                 const float* __restrict__ Wa, const float* __restrict__ ba,
                 const float* __restrict__ Wb, const float* __restrict__ bb,
                 int n) {
    __shared__ float Wt[16 * WT_STRIDE];   // 65.8 KB
    __shared__ float Xs[TN][DIM + 4];      // 33.8 KB, row stride 132 (16B aligned)
    const int tid = threadIdx.x;
    const int node0 = blockIdx.x * TN;

    // stage X tile (zero-pad OOB rows): 2048 float4s, 4 iters
    for (int i = tid; i < TN * (DIM / 4); i += MLP_THREADS) {
        const int nn = i >> 5;
        const int c4 = (i & 31) << 2;
        const int gn = node0 + nn;
        float4 v = make_float4(0.f, 0.f, 0.f, 0.f);
        if (gn < n) v = *(const float4*)(X + (size_t)gn * DIM + c4);
        *(float4*)(&Xs[nn][c4]) = v;
    }
    // stage Wa swizzled: idx = k*32 + fb*2 + half -> global addr = idx*16B (coalesced)
    for (int idx = tid; idx < DIM * 32; idx += MLP_THREADS) {
        const int k = idx >> 5, r = idx & 31, fb = r >> 1, half = r & 1;
        const float4 w = *(const float4*)(Wa + k * DIM + fb * 8 + half * 4);
        *(float4*)(&Wt[fb * WT_STRIDE + k * 8 + half * 4]) = w;
    }
    __syncthreads();

    const int fg = tid & 15, ng = tid >> 4;
    const int f0 = fg * 8, n0 = ng * 2;
    const int fgbase = fg * WT_STRIDE;

    float acc[2][8];
    {
        const float4 bA = *(const float4*)(ba + f0);
        const float4 bB = *(const float4*)(ba + f0 + 4);
        acc[0][0] = bA.x; acc[0][1] = bA.y; acc[0][2] = bA.z; acc[0][3] = bA.w;
        acc[0][4] = bB.x; acc[0][5] = bB.y; acc[0][6] = bB.z; acc[0][7] = bB.w;
        #pragma unroll
        for (int i = 0; i < 8; ++i) acc[1][i] = acc[0][i];
    }
    // GEMM 1: T = X @ Wa + ba
    #pragma unroll 4
    for (int k = 0; k < DIM; ++k) {
        const float x0 = Xs[n0][k];
        const float x1 = Xs[n0 + 1][k];
        const float4 w0 = *(const float4*)(&Wt[fgbase + k * 8]);
        const float4 w1 = *(const float4*)(&Wt[fgbase + k * 8 + 4]);
        acc[0][0] = fmaf(x0, w0.x, acc[0][0]); acc[0][1] = fmaf(x0, w0.y, acc[0][1]);
        acc[0][2] = fmaf(x0, w0.z, acc[0][2]); acc[0][3] = fmaf(x0, w0.w, acc[0][3]);
        acc[0][4] = fmaf(x0, w1.x, acc[0][4]); acc[0][5] = fmaf(x0, w1.y, acc[0][5]);
        acc[0][6] = fmaf(x0, w1.z, acc[0][6]); acc[0][7] = fmaf(x0, w1.w, acc[0][7]);
        acc[1][0] = fmaf(x1, w0.x, acc[1][0]); acc[1][1] = fmaf(x1, w0.y, acc[1][1]);
        acc[1][2] = fmaf(x1, w0.z, acc[1][2]); acc[1][3] = fmaf(x1, w0.w, acc[1][3]);
        acc[1][4] = fmaf(x1, w1.x, acc[1][4]); acc[1][5] = fmaf(x1, w1.y, acc[1][5]);
        acc[1][6] = fmaf(x1, w1.z, acc[1][6]); acc[1][7] = fmaf(x1, w1.w, acc[1][7]);
    }
    #pragma unroll
    for (int j = 0; j < 2; ++j)
        #pragma unroll
        for (int i = 0; i < 8; ++i) acc[j][i] = fmaxf(acc[j][i], 0.0f);

    __syncthreads();  // GEMM1 done reading Xs/Wt

    // write T to Xs; reload Wt with Wb
    #pragma unroll
    for (int j = 0; j < 2; ++j) {
        *(float4*)(&Xs[n0 + j][f0])     = make_float4(acc[j][0], acc[j][1], acc[j][2], acc[j][3]);
        *(float4*)(&Xs[n0 + j][f0 + 4]) = make_float4(acc[j][4], acc[j][5], acc[j][6], acc[j][7]);
    }
    for (int idx = tid; idx < DIM * 32; idx += MLP_THREADS) {
        const int k = idx >> 5, r = idx & 31, fb = r >> 1, half = r & 1;
        const float4 w = *(const float4*)(Wb + k * DIM + fb * 8 + half * 4);
        *(float4*)(&Wt[fb * WT_STRIDE + k * 8 + half * 4]) = w;
    }
    __syncthreads();

    // GEMM 2: Y = T @ Wb + bb
    {
        const float4 bA = *(const float4*)(bb + f0);
        const float4 bB = *(const float4*)(bb + f0 + 4);
        acc[0][0] = bA.x; acc[0][1] = bA.y; acc[0][2] = bA.z; acc[0][3] = bA.w;
        acc[0][4] = bB.x; acc[0][5] = bB.y; acc[0][6] = bB.z; acc[0][7] = bB.w;
        #pragma unroll
        for (int i = 0; i < 8; ++i) acc[1][i] = acc[0][i];
    }
    #pragma unroll 4
    for (int k = 0; k < DIM; ++k) {
        const float x0 = Xs[n0][k];
        const float x1 = Xs[n0 + 1][k];
        const float4 w0 = *(const float4*)(&Wt[fgbase + k * 8]);
        const float4 w1 = *(const float4*)(&Wt[fgbase + k * 8 + 4]);
        acc[0][0] = fmaf(x0, w0.x, acc[0][0]); acc[0][1] = fmaf(x0, w0.y, acc[0][1]);
        acc[0][2] = fmaf(x0, w0.z, acc[0][2]); acc[0][3] = fmaf(x0, w0.w, acc[0][3]);
        acc[0][4] = fmaf(x0, w1.x, acc[0][4]); acc[0][5] = fmaf(x0, w1.y, acc[0][5]);
        acc[0][6] = fmaf(x0, w1.z, acc[0][6]); acc[0][7] = fmaf(x0, w1.w, acc[0][7]);
        acc[1][0] = fmaf(x1, w0.x, acc[1][0]); acc[1][1] = fmaf(x1, w0.y, acc[1][1]);
        acc[1][2] = fmaf(x1, w0.z, acc[1][2]); acc[1][3] = fmaf(x1, w0.w, acc[1][3]);
        acc[1][4] = fmaf(x1, w1.x, acc[1][4]); acc[1][5] = fmaf(x1, w1.y, acc[1][5]);
        acc[1][6] = fmaf(x1, w1.z, acc[1][6]); acc[1][7] = fmaf(x1, w1.w, acc[1][7]);
    }
    #pragma unroll
    for (int j = 0; j < 2; ++j) {
        const int gn = node0 + n0 + j;
        if (gn < n) {
            *(float4*)(Y + (size_t)gn * DIM + f0)     = make_float4(acc[j][0], acc[j][1], acc[j][2], acc[j][3]);
            *(float4*)(Y + (size_t)gn * DIM + f0 + 4) = make_float4(acc[j][4], acc[j][5], acc[j][6], acc[j][7]);
        }
    }
}

// ---------------- segment mean pool (batch is sorted) ----------------
// One wave per graph; lane owns 2 columns.
__global__ __launch_bounds__(256)
void pool_kernel(const float* __restrict__ H, const int* __restrict__ goff,
                 float* __restrict__ out, int ng, int nn) {
    const int wid = (blockIdx.x * 256 + threadIdx.x) >> 6;
    const int lane = threadIdx.x & 63;
    if (wid >= ng) return;
    const int start = goff[wid];
    const int end = (wid + 1 < ng) ? goff[wid + 1] : nn;
    const int c = lane * 2;
    float2 acc = make_float2(0.f, 0.f);
    for (int nd = start; nd < end; ++nd) {
        const float2 v = *(const float2*)(H + (size_t)nd * DIM + c);
        acc.x += v.x; acc.y += v.y;
    }
    const float inv = 1.0f / fmaxf((float)(end - start), 1.0f);
    *(float2*)(out + (size_t)wid * DIM + c) = make_float2(acc.x * inv, acc.y * inv);
}

extern "C" void kernel_launch(void* const* d_in, const int* in_sizes, int n_in,
                              void* d_out, int out_size, void* d_ws, size_t ws_size,
                              hipStream_t stream) {
    const float* x     = (const float*)d_in[0];
    const int*   ei    = (const int*)d_in[1];
    const int*   batch = (const int*)d_in[2];
    const float* W1a = (const float*)d_in[3];
    const float* b1a = (const float*)d_in[4];
    const float* W1b = (const float*)d_in[5];
    const float* b1b = (const float*)d_in[6];
    const float* W2a = (const float*)d_in[7];
    const float* b2a = (const float*)d_in[8];
    const float* W2b = (const float*)d_in[9];
    const float* b2b = (const float*)d_in[10];
    float* out = (float*)d_out;

    const int NN = in_sizes[0] / DIM;    // 50000
    const int NE = in_sizes[1] / 2;      // 800000
    const int NG = out_size / DIM;       // 512

    // workspace layout
    float* bufA = (float*)d_ws;
    float* bufB = bufA + (size_t)NN * DIM;
    int*   off  = (int*)(bufB + (size_t)NN * DIM);
    int*   goff = off + NN;
    int*   csr  = goff + NG;

    const int* srcIdx = ei;
    const int* dstIdx = ei + NE;

    const int waveBlocksN = (NN * 64 + 255) / 256;   // wave per node
    const int waveBlocksG = (NG * 64 + 255) / 256;   // wave per graph
    const int mlpBlocks   = (NN + TN - 1) / TN;

    // ---- CSR + graph-offset build (once, reused by both layers) ----
    zero_int2_kernel<<<(NN + 255) / 256, 256, 0, stream>>>(off, NN, goff, NG);
    hist_kernel<<<(NE + 255) / 256, 256, 0, stream>>>(dstIdx, off, NE);
    hist_kernel<<<(NN + 255) / 256, 256, 0, stream>>>(batch, goff, NN);
    scan_excl_kernel<<<1, 1024, 0, stream>>>(off, NN);
    scan_excl_kernel<<<1, 1024, 0, stream>>>(goff, NG);
    fill_kernel<<<(NE + 255) / 256, 256, 0, stream>>>(srcIdx, dstIdx, off, csr, NE);

    // ---- layer 1 ----
    gather_kernel<<<waveBlocksN, 256, 0, stream>>>(x, csr, off, bufA, NN);
    mlp2_kernel<<<mlpBlocks, MLP_THREADS, 0, stream>>>(bufA, bufB, W1a, b1a, W1b, b1b, NN);

    // ---- layer 2 ----
    gather_kernel<<<waveBlocksN, 256, 0, stream>>>(bufB, csr, off, bufA, NN);
    mlp2_kernel<<<mlpBlocks, MLP_THREADS, 0, stream>>>(bufA, bufB, W2a, b2a, W2b, b2b, NN);

    // ---- pool (mean, direct write) ----
    pool_kernel<<<waveBlocksG, 256, 0, stream>>>(bufB, goff, out, NG, NN);
}

// Round 3
// 310.066 us; speedup vs baseline: 9.9438x; 1.4627x over previous
//
#include <hip/hip_runtime.h>

#define DIM 128

typedef unsigned short ushortT;
typedef unsigned int uintT;
typedef __attribute__((ext_vector_type(8))) __bf16 bf16x8;
typedef __attribute__((ext_vector_type(4))) float f32x4;

// ---- bf16 helpers (RNE) ----
__device__ inline ushortT f2bf(float f) {
    union { float f; uintT u; } v; v.f = f;
    uintT u = v.u;
    uintT r = (u + 0x7FFFu + ((u >> 16) & 1u)) >> 16;
    return (ushortT)r;
}
__device__ inline float bfu_lo(uintT u) { union { uintT u; float f; } v; v.u = u << 16; return v.f; }
__device__ inline float bfu_hi(uintT u) { union { uintT u; float f; } v; v.u = u & 0xffff0000u; return v.f; }

// ---- interleaved row layout (256 B per node row of 128 bf16) ----
// chunk(ks,g) [16B] holds k in {32ks+4g+0..3} (bytes 0-7) and {32ks+16+4g+0..3} (bytes 8-15)
// matching the mfma_f32_16x16x32_bf16 per-lane k-split. XOR-swizzle ((row&7)<<4) baked in.
__device__ inline int off_in_row(int k) {
    return (((k >> 5) * 4 + ((k & 15) >> 2)) << 4) + (((k >> 4) & 1) << 3) + ((k & 3) << 1);
}

// ================= CSR build =================
__global__ __launch_bounds__(256)
void zero_int2_kernel(int* __restrict__ a, int na, int* __restrict__ b, int nb) {
    int i = blockIdx.x * 256 + threadIdx.x;
    if (i < na) a[i] = 0;
    if (i < nb) b[i] = 0;
}

__global__ __launch_bounds__(256)
void hist_kernel(const int* __restrict__ idx, int* __restrict__ cnt, int n) {
    int i = blockIdx.x * 256 + threadIdx.x;
    if (i < n) atomicAdd(&cnt[idx[i]], 1);
}

__device__ inline int wave_iscan(int v) {
    int lane = threadIdx.x & 63;
    #pragma unroll
    for (int d = 1; d < 64; d <<= 1) {
        int t = __shfl_up(v, d, 64);
        if (lane >= d) v += t;
    }
    return v;
}

__global__ __launch_bounds__(256)
void scan_blk_kernel(int* __restrict__ a, int n, int* __restrict__ bsum) {
    __shared__ int ws[4];
    const int tid = threadIdx.x;
    const int i = blockIdx.x * 256 + tid;
    const int lane = tid & 63, wv = tid >> 6;
    int v = (i < n) ? a[i] : 0;
    int isc = wave_iscan(v);
    if (lane == 63) ws[wv] = isc;
    __syncthreads();
    if (tid == 0) { int run = 0; for (int w = 0; w < 4; ++w) { int t = ws[w]; ws[w] = run; run += t; } }
    __syncthreads();
    int e = ws[wv] + isc - v;
    if (i < n) a[i] = e;
    if (tid == 255) bsum[blockIdx.x] = e + v;
}

__global__ __launch_bounds__(256)
void scan_mid_kernel(int* __restrict__ b, int nb) {
    __shared__ int ws[4];
    const int tid = threadIdx.x;
    const int lane = tid & 63, wv = tid >> 6;
    int v = (tid < nb) ? b[tid] : 0;
    int isc = wave_iscan(v);
    if (lane == 63) ws[wv] = isc;
    __syncthreads();
    if (tid == 0) { int run = 0; for (int w = 0; w < 4; ++w) { int t = ws[w]; ws[w] = run; run += t; } }
    __syncthreads();
    int e = ws[wv] + isc - v;
    if (tid < nb) b[tid] = e;
}

__global__ __launch_bounds__(256)
void scan_add_kernel(int* __restrict__ a, int n, const int* __restrict__ bsum) {
    int i = blockIdx.x * 256 + threadIdx.x;
    if (i < n) a[i] += bsum[blockIdx.x];
}

__global__ __launch_bounds__(512)
void scan_small_kernel(int* __restrict__ a, int n) {
    __shared__ int ws[8];
    const int tid = threadIdx.x;
    const int lane = tid & 63, wv = tid >> 6;
    int v = (tid < n) ? a[tid] : 0;
    int isc = wave_iscan(v);
    if (lane == 63) ws[wv] = isc;
    __syncthreads();
    if (tid == 0) { int run = 0; for (int w = 0; w < 8; ++w) { int t = ws[w]; ws[w] = run; run += t; } }
    __syncthreads();
    int e = ws[wv] + isc - v;
    if (tid < n) a[tid] = e;
}

__global__ __launch_bounds__(256)
void fill_kernel(const int* __restrict__ srcIdx, const int* __restrict__ dstIdx,
                 int* __restrict__ off, int* __restrict__ csr, int ne) {
    int e = blockIdx.x * 256 + threadIdx.x;
    if (e < ne) {
        int p = atomicAdd(&off[dstIdx[e]], 1);
        csr[p] = srcIdx[e];
    }
}

// ================= layout conversion =================
// x f32 [node][128] -> xb bf16 interleaved+swizzled rows
__global__ __launch_bounds__(256)
void convert_x_kernel(const float* __restrict__ x, ushortT* __restrict__ xb, int n) {
    int i = blockIdx.x * 256 + threadIdx.x;
    int node = i >> 6, p = i & 63;
    if (node >= n) return;
    float2 v = *(const float2*)(x + (size_t)node * DIM + 2 * p);
    uintT u = ((uintT)f2bf(v.y) << 16) | f2bf(v.x);
    char* base = (char*)xb;
    *(uintT*)(base + (size_t)node * 256 + (off_in_row(2 * p) ^ ((node & 7) << 4))) = u;
}

// W f32 [k][n] -> Wt2 bf16 interleaved+swizzled rows indexed by n (i.e. W^T image)
__global__ __launch_bounds__(256)
void prep_w_kernel(const float* __restrict__ W, ushortT* __restrict__ Wt2) {
    int i = blockIdx.x * 256 + threadIdx.x;   // 8192 total
    if (i >= DIM * 64) return;
    int nidx = i >> 6, p = i & 63, k = 2 * p;
    float w0 = W[k * DIM + nidx];
    float w1 = W[(k + 1) * DIM + nidx];
    uintT u = ((uintT)f2bf(w1) << 16) | f2bf(w0);
    char* base = (char*)Wt2;
    *(uintT*)(base + (size_t)nidx * 256 + (off_in_row(k) ^ ((nidx & 7) << 4))) = u;
}

// ================= gather: H[n] = X[n] + sum_{CSR(n)} X[src] (bf16 rows, f32 acc) =================
__global__ __launch_bounds__(256)
void gather_kernel(const ushortT* __restrict__ X, const int* __restrict__ csr,
                   const int* __restrict__ off, ushortT* __restrict__ H, int n) {
    const int wid = (blockIdx.x * 256 + threadIdx.x) >> 6;
    const int lane = threadIdx.x & 63;
    if (wid >= n) return;
    const int start = (wid > 0) ? off[wid - 1] : 0;
    const int end = off[wid];
    const int bo = off_in_row(2 * lane);
    const char* Xc = (const char*)X;
    uintT u0 = *(const uintT*)(Xc + (size_t)wid * 256 + (bo ^ ((wid & 7) << 4)));
    float a0 = bfu_lo(u0), a1 = bfu_hi(u0);
    int e = start;
    for (; e + 4 <= end; e += 4) {
        const int s0 = csr[e], s1 = csr[e + 1], s2 = csr[e + 2], s3 = csr[e + 3];
        uintT v0 = *(const uintT*)(Xc + (size_t)s0 * 256 + (bo ^ ((s0 & 7) << 4)));
        uintT v1 = *(const uintT*)(Xc + (size_t)s1 * 256 + (bo ^ ((s1 & 7) << 4)));
        uintT v2 = *(const uintT*)(Xc + (size_t)s2 * 256 + (bo ^ ((s2 & 7) << 4)));
        uintT v3 = *(const uintT*)(Xc + (size_t)s3 * 256 + (bo ^ ((s3 & 7) << 4)));
        a0 += (bfu_lo(v0) + bfu_lo(v1)) + (bfu_lo(v2) + bfu_lo(v3));
        a1 += (bfu_hi(v0) + bfu_hi(v1)) + (bfu_hi(v2) + bfu_hi(v3));
    }
    for (; e < end; ++e) {
        const int s = csr[e];
        uintT v = *(const uintT*)(Xc + (size_t)s * 256 + (bo ^ ((s & 7) << 4)));
        a0 += bfu_lo(v); a1 += bfu_hi(v);
    }
    uintT out = ((uintT)f2bf(a1) << 16) | f2bf(a0);
    *(uintT*)((char*)H + (size_t)wid * 256 + (bo ^ ((wid & 7) << 4))) = out;
}

// ================= MFMA MLP: Y = relu(X@Wa + ba) @ Wb + bb =================
// 256 threads (4 waves), 64 nodes/block, wave tile 32x64.
__global__ __launch_bounds__(256)
void mlp_mfma_kernel(const ushortT* __restrict__ Xg, ushortT* __restrict__ Yg,
                     const ushortT* __restrict__ Wta, const float* __restrict__ ba,
                     const ushortT* __restrict__ Wtb, const float* __restrict__ bb,
                     int n) {
    __shared__ __align__(16) ushortT XsU[64 * DIM];    // 16 KB (also holds T after GEMM1)
    __shared__ __align__(16) ushortT WtU[DIM * DIM];   // 32 KB
    const int tid = threadIdx.x;
    const int node0 = blockIdx.x * 64;
    const int lane = tid & 63, wid = tid >> 6;
    const int l15 = lane & 15, g = lane >> 4;
    const int RB = (wid >> 1) * 32, CB = (wid & 1) * 64;

    // stage X tile (linear copy; layout pre-baked in global)
    #pragma unroll
    for (int it = 0; it < 4; ++it) {
        int idx = tid + it * 256;
        *(uint4*)(XsU + idx * 8) = *(const uint4*)(Xg + (size_t)node0 * DIM + idx * 8);
    }
    // stage Wa^T image
    #pragma unroll
    for (int it = 0; it < 8; ++it) {
        int idx = tid + it * 256;
        *(uint4*)(WtU + idx * 8) = *(const uint4*)(Wta + idx * 8);
    }
    __syncthreads();

    const char* Xc = (const char*)XsU;
    const char* Wc = (const char*)WtU;

    f32x4 acc[2][4];
    #pragma unroll
    for (int nt = 0; nt < 4; ++nt) {
        float bv = ba[CB + nt * 16 + l15];
        #pragma unroll
        for (int mt = 0; mt < 2; ++mt) acc[mt][nt] = (f32x4){bv, bv, bv, bv};
    }

    // GEMM 1
    #pragma unroll
    for (int ks = 0; ks < 4; ++ks) {
        const int cb = (ks * 4 + g) << 4;
        bf16x8 a0, a1, b[4];
        {
            int r0 = RB + l15, r1 = RB + 16 + l15;
            a0 = *(const bf16x8*)(Xc + r0 * 256 + (cb ^ ((r0 & 7) << 4)));
            a1 = *(const bf16x8*)(Xc + r1 * 256 + (cb ^ ((r1 & 7) << 4)));
        }
        #pragma unroll
        for (int nt = 0; nt < 4; ++nt) {
            int rn = CB + nt * 16 + l15;
            b[nt] = *(const bf16x8*)(Wc + rn * 256 + (cb ^ ((rn & 7) << 4)));
        }
        #pragma unroll
        for (int nt = 0; nt < 4; ++nt) {
            acc[0][nt] = __builtin_amdgcn_mfma_f32_16x16x32_bf16(a0, b[nt], acc[0][nt], 0, 0, 0);
            acc[1][nt] = __builtin_amdgcn_mfma_f32_16x16x32_bf16(a1, b[nt], acc[1][nt], 0, 0, 0);
        }
    }
    // ReLU
    #pragma unroll
    for (int mt = 0; mt < 2; ++mt)
        #pragma unroll
        for (int nt = 0; nt < 4; ++nt)
            #pragma unroll
            for (int c = 0; c < 4; ++c) acc[mt][nt][c] = fmaxf(acc[mt][nt][c], 0.0f);

    __syncthreads();   // all waves done reading Xs/Wt for GEMM1

    // write T into XsU (interleaved+swizzled), restage Wt with Wb^T
    #pragma unroll
    for (int nt = 0; nt < 4; ++nt) {
        const int k = CB + nt * 16 + l15;
        const int offk = off_in_row(k);
        #pragma unroll
        for (int mt = 0; mt < 2; ++mt) {
            #pragma unroll
            for (int r = 0; r < 4; ++r) {
                int row = RB + mt * 16 + 4 * g + r;
                *(ushortT*)((char*)XsU + row * 256 + (offk ^ ((row & 7) << 4))) = f2bf(acc[mt][nt][r]);
            }
        }
    }
    #pragma unroll
    for (int it = 0; it < 8; ++it) {
        int idx = tid + it * 256;
        *(uint4*)(WtU + idx * 8) = *(const uint4*)(Wtb + idx * 8);
    }
    __syncthreads();

    // GEMM 2
    #pragma unroll
    for (int nt = 0; nt < 4; ++nt) {
        float bv = bb[CB + nt * 16 + l15];
        #pragma unroll
        for (int mt = 0; mt < 2; ++mt) acc[mt][nt] = (f32x4){bv, bv, bv, bv};
    }
    #pragma unroll
    for (int ks = 0; ks < 4; ++ks) {
        const int cb = (ks * 4 + g) << 4;
        bf16x8 a0, a1, b[4];
        {
            int r0 = RB + l15, r1 = RB + 16 + l15;
            a0 = *(const bf16x8*)(Xc + r0 * 256 + (cb ^ ((r0 & 7) << 4)));
            a1 = *(const bf16x8*)(Xc + r1 * 256 + (cb ^ ((r1 & 7) << 4)));
        }
        #pragma unroll
        for (int nt = 0; nt < 4; ++nt) {
            int rn = CB + nt * 16 + l15;
            b[nt] = *(const bf16x8*)(Wc + rn * 256 + (cb ^ ((rn & 7) << 4)));
        }
        #pragma unroll
        for (int nt = 0; nt < 4; ++nt) {
            acc[0][nt] = __builtin_amdgcn_mfma_f32_16x16x32_bf16(a0, b[nt], acc[0][nt], 0, 0, 0);
            acc[1][nt] = __builtin_amdgcn_mfma_f32_16x16x32_bf16(a1, b[nt], acc[1][nt], 0, 0, 0);
        }
    }
    // store Y (bf16, interleaved+swizzled), masked
    #pragma unroll
    for (int nt = 0; nt < 4; ++nt) {
        const int k = CB + nt * 16 + l15;
        const int offk = off_in_row(k);
        #pragma unroll
        for (int mt = 0; mt < 2; ++mt) {
            #pragma unroll
            for (int r = 0; r < 4; ++r) {
                int row = RB + mt * 16 + 4 * g + r;
                int node = node0 + row;
                if (node < n)
                    *(ushortT*)((char*)Yg + (size_t)node * 256 + (offk ^ ((row & 7) << 4))) = f2bf(acc[mt][nt][r]);
            }
        }
    }
}

// ================= mean pool (batch sorted; goff = exclusive offsets) =================
__global__ __launch_bounds__(256)
void pool_kernel(const ushortT* __restrict__ H, const int* __restrict__ goff,
                 float* __restrict__ out, int ng, int nn) {
    const int wid = (blockIdx.x * 256 + threadIdx.x) >> 6;
    const int lane = threadIdx.x & 63;
    if (wid >= ng) return;
    const int start = goff[wid];
    const int end = (wid + 1 < ng) ? goff[wid + 1] : nn;
    const int bo = off_in_row(2 * lane);
    const char* Hc = (const char*)H;
    float a0 = 0.f, a1 = 0.f;
    for (int nd = start; nd < end; ++nd) {
        uintT v = *(const uintT*)(Hc + (size_t)nd * 256 + (bo ^ ((nd & 7) << 4)));
        a0 += bfu_lo(v); a1 += bfu_hi(v);
    }
    const float inv = 1.0f / fmaxf((float)(end - start), 1.0f);
    *(float2*)(out + (size_t)wid * DIM + 2 * lane) = make_float2(a0 * inv, a1 * inv);
}

extern "C" void kernel_launch(void* const* d_in, const int* in_sizes, int n_in,
                              void* d_out, int out_size, void* d_ws, size_t ws_size,
                              hipStream_t stream) {
    const float* x     = (const float*)d_in[0];
    const int*   ei    = (const int*)d_in[1];
    const int*   batch = (const int*)d_in[2];
    const float* W1a = (const float*)d_in[3];
    const float* b1a = (const float*)d_in[4];
    const float* W1b = (const float*)d_in[5];
    const float* b1b = (const float*)d_in[6];
    const float* W2a = (const float*)d_in[7];
    const float* b2a = (const float*)d_in[8];
    const float* W2b = (const float*)d_in[9];
    const float* b2b = (const float*)d_in[10];
    float* out = (float*)d_out;

    const int NN = in_sizes[0] / DIM;     // 50000
    const int NE = in_sizes[1] / 2;       // 800000
    const int NG = out_size / DIM;        // 512
    const int NN2 = (NN + 63) & ~63;      // padded rows for MLP tile staging

    // workspace layout (bf16 rows are 128 ushorts = 256 B)
    ushortT* xb   = (ushortT*)d_ws;
    ushortT* bufA = xb   + (size_t)NN2 * DIM;
    ushortT* bufB = bufA + (size_t)NN2 * DIM;
    ushortT* wt   = bufB + (size_t)NN2 * DIM;        // 4 × 128×128
    int* off  = (int*)(wt + 4 * DIM * DIM);
    int* goff = off + NN;
    int* bsum = goff + NG;
    int* csr  = bsum + 256;

    const int* srcIdx = ei;
    const int* dstIdx = ei + NE;

    const int nScanBlk = (NN + 255) / 256;           // 196

    // ---- CSR + graph offsets ----
    zero_int2_kernel<<<(NN + 255) / 256, 256, 0, stream>>>(off, NN, goff, NG);
    hist_kernel<<<(NE + 255) / 256, 256, 0, stream>>>(dstIdx, off, NE);
    hist_kernel<<<(NN + 255) / 256, 256, 0, stream>>>(batch, goff, NN);
    scan_blk_kernel<<<nScanBlk, 256, 0, stream>>>(off, NN, bsum);
    scan_mid_kernel<<<1, 256, 0, stream>>>(bsum, nScanBlk);
    scan_add_kernel<<<nScanBlk, 256, 0, stream>>>(off, NN, bsum);
    scan_small_kernel<<<1, 512, 0, stream>>>(goff, NG);
    fill_kernel<<<(NE + 255) / 256, 256, 0, stream>>>(srcIdx, dstIdx, off, csr, NE);

    // ---- layout prep ----
    convert_x_kernel<<<(NN * 64 + 255) / 256, 256, 0, stream>>>(x, xb, NN);
    prep_w_kernel<<<32, 256, 0, stream>>>(W1a, wt);
    prep_w_kernel<<<32, 256, 0, stream>>>(W1b, wt + DIM * DIM);
    prep_w_kernel<<<32, 256, 0, stream>>>(W2a, wt + 2 * DIM * DIM);
    prep_w_kernel<<<32, 256, 0, stream>>>(W2b, wt + 3 * DIM * DIM);

    const int gatherBlocks = (NN * 64 + 255) / 256;
    const int mlpBlocks = (NN + 63) / 64;

    // ---- layer 1 ----
    gather_kernel<<<gatherBlocks, 256, 0, stream>>>(xb, csr, off, bufA, NN);
    mlp_mfma_kernel<<<mlpBlocks, 256, 0, stream>>>(bufA, bufB, wt, b1a, wt + DIM * DIM, b1b, NN);

    // ---- layer 2 ----
    gather_kernel<<<gatherBlocks, 256, 0, stream>>>(bufB, csr, off, bufA, NN);
    mlp_mfma_kernel<<<mlpBlocks, 256, 0, stream>>>(bufA, xb, wt + 2 * DIM * DIM, b2a, wt + 3 * DIM * DIM, b2b, NN);

    // ---- pool ----
    pool_kernel<<<(NG * 64 + 255) / 256, 256, 0, stream>>>(xb, goff, out, NG, NN);
}